// Round 12
// baseline (232.812 us; speedup 1.0000x reference)
//
#include <hip/hip_runtime.h>
#include <hip/hip_bf16.h>

// Problem constants
#define NT 4301   // total tokens
#define NP 4201   // patch tokens (use *_p weights)
#define NDET 100  // detection tokens (use *_d weights)
#define DMODEL 768
#define NHEAD 12
#define HD 64
#define LN_EPS 1e-5f
#define LOG2E 1.4426950408889634f
#define QSCALE (0.125f * LOG2E)   // attn scale folded with log2(e): softmax in exp2 domain
#define NTP 4352                  // padded token count (34*128 = 68*64)
#define NCHUNK 68                 // ceil(4301/64)
#define FRAGSZ 512                // elems per frag blob: 64 lanes x 8 bf16
#define CHUNKSZ 4096              // elems per (head,chunk): 8 frags x 512

typedef __hip_bfloat16 bf16;
typedef __attribute__((ext_vector_type(4))) float f32x4;
typedef __attribute__((ext_vector_type(8))) short frag8;  // 8 bf16 in 4 VGPRs
typedef __attribute__((ext_vector_type(2))) unsigned int u32x2;

// permlane swap helpers (gfx950). Builtin returns {new_dst, new_src}; both used.
static __device__ __forceinline__ void permlane32_swap(unsigned& a, unsigned& b) {
#if __has_builtin(__builtin_amdgcn_permlane32_swap)
    u32x2 r = __builtin_amdgcn_permlane32_swap(a, b, false, false);
    a = r[0]; b = r[1];
#else
    asm("v_permlane32_swap_b32 %0, %1" : "+v"(a), "+v"(b));
#endif
}
static __device__ __forceinline__ void permlane16_swap(unsigned& a, unsigned& b) {
#if __has_builtin(__builtin_amdgcn_permlane16_swap)
    u32x2 r = __builtin_amdgcn_permlane16_swap(a, b, false, false);
    a = r[0]; b = r[1];
#else
    asm("v_permlane16_swap_b32 %0, %1" : "+v"(a), "+v"(b));
#endif
}

// native exp2 (no OCML guard code); v_exp_f32 handles the full f32 range.
static __device__ __forceinline__ float fast_exp2(float x) {
#if __has_builtin(__builtin_amdgcn_exp2f)
    return __builtin_amdgcn_exp2f(x);
#else
    return __builtin_exp2f(x);
#endif
}

// Pack two f32 -> bf16x2 (a -> low16, b -> high16) in ONE v_perm_b32.
// Truncation (no round-to-nearest): softmax divides sum(P*V) by sum(P), so
// the uniform downward bias ~cancels; saves 2 VALU adds per pair vs
// round-half-up.
static __device__ __forceinline__ unsigned pack_bf16_tr(float a, float b) {
    return __builtin_amdgcn_perm(__builtin_bit_cast(unsigned, b),
                                 __builtin_bit_cast(unsigned, a), 0x07060302u);
}

// async global->LDS, 16B per lane. LDS dest = wave-uniform base + lane*16
// (m104); global src is per-lane.
static __device__ __forceinline__ void gload16(const bf16* g, bf16* l) {
    __builtin_amdgcn_global_load_lds(
        (const __attribute__((address_space(1))) void*)g,
        (__attribute__((address_space(3))) void*)l, 16, 0, 0);
}

// ---------------------------------------------------------------------------
// One fused cast: x + 8 weight matrices fp32->bf16 into contiguous ws region
// ---------------------------------------------------------------------------
__global__ __launch_bounds__(256) void cast_all_kernel(
    const float* __restrict__ x,
    const float* __restrict__ w0, const float* __restrict__ w1,
    const float* __restrict__ w2, const float* __restrict__ w3,
    const float* __restrict__ w4, const float* __restrict__ w5,
    const float* __restrict__ w6, const float* __restrict__ w7,
    bf16* __restrict__ dst, int nx, int nw, int total) {
    int i4 = (blockIdx.x * 256 + threadIdx.x) * 4;
    if (i4 >= total) return;
    const float* s;
    int off;
    if (i4 < nx) {
        s = x; off = i4;
    } else {
        int r = i4 - nx;
        int w = r / nw;
        off = r - w * nw;
        s = w0;
        if (w == 1) s = w1; else if (w == 2) s = w2; else if (w == 3) s = w3;
        else if (w == 4) s = w4; else if (w == 5) s = w5;
        else if (w == 6) s = w6; else if (w == 7) s = w7;
    }
    float4 v = *(const float4*)(s + off);
    bf16 o[4] = {__float2bfloat16(v.x), __float2bfloat16(v.y),
                 __float2bfloat16(v.z), __float2bfloat16(v.w)};
    *(ushort4*)(dst + i4) = *(ushort4*)o;
}

// ---------------------------------------------------------------------------
// Fused QKV v3: gload_lds double-buffered staging, ONE barrier per K-step.
// grid = (68, 12). Outputs: Q*QSCALE row-major; K/V pre-swizzled frag order.
// ---------------------------------------------------------------------------
__global__ __launch_bounds__(256, 4) void qkv_kernel(
    const bf16* __restrict__ xb, const bf16* __restrict__ wbase,
    const float* __restrict__ bq_p, const float* __restrict__ bq_d,
    const float* __restrict__ bv_p, const float* __restrict__ bv_d,
    bf16* __restrict__ Qb, bf16* __restrict__ Ksw, bf16* __restrict__ Vsw) {
    __shared__ bf16 As[2][64][32];
    __shared__ bf16 Bs[2][192][32];   // rows 0-63: wq, 64-127: wk, 128-191: wv

    const int tid = threadIdx.x;
    const int wave = tid >> 6, lane = tid & 63;
    const int quad = lane >> 4, l16 = lane & 15;
    const int bx = blockIdx.x;
    const int h = blockIdx.y;
    const int is_det = bx >= 66;
    const int row0 = is_det ? NP + (bx - 66) * 64 : bx * 64;
    const int Mlim = is_det ? NT : NP;
    const int col0 = h * 64;
    const size_t nw = (size_t)DMODEL * DMODEL;
    const bf16* W = wbase + (is_det ? 3 * nw : 0);

    const f32x4 z4 = {0.f, 0.f, 0.f, 0.f};
    f32x4 acc[4][3];
#pragma unroll
    for (int r4 = 0; r4 < 4; ++r4)
#pragma unroll
        for (int f = 0; f < 3; ++f) acc[r4][f] = z4;

    const int srow = tid >> 2;          // 0..63
    const int scol8 = (tid & 3) * 8;    // 0,8,16,24
    int a_r = row0 + srow;
    if (a_r >= Mlim) a_r = Mlim - 1;
    const bf16* ap = xb + (size_t)a_r * DMODEL + scol8;
    const bf16* bp = W + (size_t)(col0 + srow) * DMODEL + scol8;

    // wave-uniform LDS bases (each wave stages its 1 KB quarter per region)
    bf16* asb[2] = {&As[0][0][0] + wave * 512, &As[1][0][0] + wave * 512};
    bf16* bsb[2] = {&Bs[0][0][0] + wave * 512, &Bs[1][0][0] + wave * 512};

    // prologue: stage k0=0 into buffer 0
    {
        gload16(ap, asb[0]);
        gload16(bp, bsb[0]);
        gload16(bp + nw, bsb[0] + 2048);
        gload16(bp + 2 * nw, bsb[0] + 4096);
    }
    __asm__ volatile("s_waitcnt vmcnt(0)" ::: "memory");
    __builtin_amdgcn_s_barrier();
    __asm__ volatile("" ::: "memory");

    int p = 0;
    for (int k0 = 0; k0 < DMODEL; k0 += 32) {
        if (k0 + 32 < DMODEL) {
            const int kn = k0 + 32;
            gload16(ap + kn, asb[p ^ 1]);
            gload16(bp + kn, bsb[p ^ 1]);
            gload16(bp + nw + kn, bsb[p ^ 1] + 2048);
            gload16(bp + 2 * nw + kn, bsb[p ^ 1] + 4096);
        }
        frag8 af[4], bfr[3];
#pragma unroll
        for (int r4 = 0; r4 < 4; ++r4)
            af[r4] = *(const frag8*)(&As[p][r4 * 16 + l16][quad * 8]);
#pragma unroll
        for (int f = 0; f < 3; ++f)
            bfr[f] = *(const frag8*)(&Bs[p][wave * 48 + f * 16 + l16][quad * 8]);
#pragma unroll
        for (int r4 = 0; r4 < 4; ++r4)
#pragma unroll
            for (int f = 0; f < 3; ++f)
                acc[r4][f] = __builtin_amdgcn_mfma_f32_16x16x32_bf16(af[r4], bfr[f], acc[r4][f], 0, 0, 0);
        // single barrier: next-step stage writes landed; all waves done reading p
        __asm__ volatile("s_waitcnt vmcnt(0)" ::: "memory");
        __builtin_amdgcn_s_barrier();
        __asm__ volatile("" ::: "memory");
        p ^= 1;
    }

    // epilogue: wave w covers logical cols [w*48, w*48+48); 16-col group oc=3w+f
#pragma unroll
    for (int f = 0; f < 3; ++f) {
        const int oc = 3 * wave + f;          // 0..11
        const int opi = oc >> 2;              // 0=Q 1=K 2=V
        const int cin = (oc & 3) * 16 + l16;  // head-dim 0..63
        const int c = col0 + cin;             // global dim
        float bv = 0.f, scale = 1.f;
        if (opi == 0) { bv = (is_det ? bq_d : bq_p)[c]; scale = QSCALE; }
        else if (opi == 2) { bv = (is_det ? bv_d : bv_p)[c]; }
#pragma unroll
        for (int r4 = 0; r4 < 4; ++r4) {
#pragma unroll
            for (int j = 0; j < 4; ++j) {
                const int r = row0 + r4 * 16 + quad * 4 + j;
                if (r >= Mlim) continue;
                const bf16 val = __float2bfloat16((acc[r4][f][j] + bv) * scale);
                if (opi == 0) {
                    Qb[(size_t)r * DMODEL + c] = val;
                } else if (opi == 1) {
                    const int cc = r >> 6, tf = (r >> 4) & 3, ln = r & 15;
                    const int s = cin >> 5, qd = (cin >> 3) & 3, je = cin & 7;
                    Ksw[((size_t)(h * NCHUNK + cc) * 8 + tf * 2 + s) * FRAGSZ +
                        (qd * 16 + ln) * 8 + je] = val;
                } else {
                    const int t = cin >> 4, le = cin & 15;
                    const int cc = r >> 6, rr = r & 63;
                    const int sv = rr >> 5, qv = (rr >> 3) & 3, je = rr & 7;
                    Vsw[((size_t)(h * NCHUNK + cc) * 8 + t * 2 + sv) * FRAGSZ +
                        (qv * 16 + le) * 8 + je] = val;
                }
            }
        }
    }
}

// ---------------------------------------------------------------------------
// Flash attention v16 (R9/R10 best, unchanged): 4-wave/256-thr blocks, 128
// q-rows, 32 KB double-buffered K/V via gload_lds, one barrier per chunk,
// swapped QK^T + in-register P (permlane), truncating pack.
// ---------------------------------------------------------------------------
__global__ __launch_bounds__(256, 4) void attn_kernel(
    const bf16* __restrict__ Q, const bf16* __restrict__ Ksw,
    const bf16* __restrict__ Vsw, float* __restrict__ O_part,
    float* __restrict__ l_part, int cpb) {
    __shared__ bf16 KV[2][16][FRAGSZ];   // [buf][frag: 0-7 K, 8-15 V][lane*8]

    const int tid = threadIdx.x;
    const int wave = tid >> 6, lane = tid & 63;
    const int quad = lane >> 4, l16 = lane & 15;

    // decode (bx, h, z) from 1D id; XCD-chunked when blocks/XCD % 34 == 0
    int bx, h, z;
    {
        const int id = blockIdx.x;
        const int nblk = gridDim.x;
        const int per = nblk >> 3;
        if ((nblk & 7) == 0 && per % 34 == 0) {
            const int ppx = per / 34;                 // (h,z) pairs per XCD
            const int q = id >> 3;
            const int pair = (id & 7) * ppx + q / 34;
            bx = q % 34;
            h = pair % NHEAD; z = pair / NHEAD;
        } else {
            bx = id % 34; h = (id / 34) % NHEAD; z = id / (34 * NHEAD);
        }
    }
    const int qbase = bx * 128;
    const int hoff = h * HD;
    const int c0 = z * cpb, c1 = c0 + cpb;

    frag8 ones;
#pragma unroll
    for (int j = 0; j < 8; ++j) ones[j] = (short)0x3F80;

    // Q fragments for 2 row-groups: rows qbase + wave*32 + g*16 + l16.
    frag8 qf[2][2];
#pragma unroll
    for (int g = 0; g < 2; ++g) {
        int qr = qbase + wave * 32 + g * 16 + l16;
        if (qr >= NT) qr = NT - 1;
#pragma unroll
        for (int s = 0; s < 2; ++s)
            qf[g][s] = *(const frag8*)(Q + (size_t)qr * DMODEL + hoff + s * 32 + quad * 8);
    }

    // staging: wave 0/1 -> K frags 0-3/4-7, wave 2/3 -> V frags 0-3/4-7.
    const bf16* kb0 = Ksw + (size_t)h * NCHUNK * CHUNKSZ + lane * 8;
    const bf16* vb0 = Vsw + (size_t)h * NCHUNK * CHUNKSZ + lane * 8;
    const bf16* sb = (wave < 2) ? kb0 : vb0;
    const int foff = (wave & 1) * 4;      // frag index within K or V blob
    const int fbase = 4 * wave;           // LDS frag row

    const f32x4 z4 = {0.f, 0.f, 0.f, 0.f};
    f32x4 accO[2][4], accL[2];
#pragma unroll
    for (int g = 0; g < 2; ++g) {
        accL[g] = z4;
#pragma unroll
        for (int t = 0; t < 4; ++t) accO[g][t] = z4;
    }

    // prologue: stage chunk c0 into buffer 0, drain, sync
    {
        const bf16* s = sb + (size_t)c0 * CHUNKSZ + foff * FRAGSZ;
#pragma unroll
        for (int i = 0; i < 4; ++i)
            gload16(s + i * FRAGSZ, &KV[0][fbase + i][0]);
    }
    __asm__ volatile("s_waitcnt vmcnt(0)" ::: "memory");
    __builtin_amdgcn_s_barrier();
    __asm__ volatile("" ::: "memory");

    int p = 0;
    for (int c = c0; c < c1; ++c) {
        // stage next chunk into the other buffer; flight hidden under compute
        if (c + 1 < c1) {
            const bf16* s = sb + (size_t)(c + 1) * CHUNKSZ + foff * FRAGSZ;
#pragma unroll
            for (int i = 0; i < 4; ++i)
                gload16(s + i * FRAGSZ, &KV[p ^ 1][fbase + i][0]);
        }

        // S^T = K @ Q^T; kf read per-t at point of use (8 live K VGPRs)
        f32x4 S[2][4];
#pragma unroll
        for (int t = 0; t < 4; ++t) {
            const frag8 k0 = *(const frag8*)(&KV[p][t * 2 + 0][lane * 8]);
            const frag8 k1 = *(const frag8*)(&KV[p][t * 2 + 1][lane * 8]);
#pragma unroll
            for (int g = 0; g < 2; ++g) {
                f32x4 s0 = __builtin_amdgcn_mfma_f32_16x16x32_bf16(k0, qf[g][0], z4, 0, 0, 0);
                S[g][t]  = __builtin_amdgcn_mfma_f32_16x16x32_bf16(k1, qf[g][1], s0, 0, 0, 0);
            }
        }
        if (c == NCHUNK - 1) {
            const int kb = c * 64 + quad * 4;   // k row index base for this lane
#pragma unroll
            for (int t = 0; t < 4; ++t)
#pragma unroll
                for (int j = 0; j < 4; ++j)
                    if (kb + t * 16 + j >= NT) {
                        S[0][t][j] = -1e30f;
                        S[1][t][j] = -1e30f;
                    }
        }

        // softmax: exp2 -> 1-op truncating pack -> permlane assembly
        frag8 pf[2][2];   // [g][s]
#pragma unroll
        for (int g = 0; g < 2; ++g) {
            unsigned lo[4], hi[4];
#pragma unroll
            for (int t = 0; t < 4; ++t) {
                lo[t] = pack_bf16_tr(fast_exp2(S[g][t][0]), fast_exp2(S[g][t][1]));
                hi[t] = pack_bf16_tr(fast_exp2(S[g][t][2]), fast_exp2(S[g][t][3]));
            }
#pragma unroll
            for (int s = 0; s < 2; ++s) {
                unsigned A = lo[2 * s], B = hi[2 * s];
                unsigned C = lo[2 * s + 1], D = hi[2 * s + 1];
                permlane32_swap(A, C);
                permlane32_swap(B, D);
                permlane16_swap(A, C);
                permlane16_swap(B, D);
                union { unsigned u[4]; frag8 f; } pu;
                pu.u[0] = A; pu.u[1] = B; pu.u[2] = C; pu.u[3] = D;
                pf[g][s] = pu.f;
                accL[g] = __builtin_amdgcn_mfma_f32_16x16x32_bf16(pf[g][s], ones, accL[g], 0, 0, 0);
            }
        }

        // O += P @ V ; vf read per (s,t), shared across both row-groups
#pragma unroll
        for (int s = 0; s < 2; ++s)
#pragma unroll
            for (int t = 0; t < 4; ++t) {
                const frag8 v = *(const frag8*)(&KV[p][8 + t * 2 + s][lane * 8]);
#pragma unroll
                for (int g = 0; g < 2; ++g)
                    accO[g][t] = __builtin_amdgcn_mfma_f32_16x16x32_bf16(pf[g][s], v, accO[g][t], 0, 0, 0);
            }

        // single barrier per chunk: stage writes landed (vmcnt 0, hidden
        // under the compute above) and every wave is done reading buf p.
        __asm__ volatile("s_waitcnt vmcnt(0)" ::: "memory");
        __builtin_amdgcn_s_barrier();
        __asm__ volatile("" ::: "memory");
        p ^= 1;
    }

    // write fp32 partials
    float* Op = O_part + (size_t)z * NT * DMODEL;
#pragma unroll
    for (int g = 0; g < 2; ++g)
#pragma unroll
        for (int j = 0; j < 4; ++j) {
            const int r = qbase + wave * 32 + g * 16 + quad * 4 + j;
            if (r < NT) {
#pragma unroll
                for (int t = 0; t < 4; ++t)
                    Op[(size_t)r * DMODEL + hoff + t * 16 + l16] = accO[g][t][j];
                if (l16 == 0)
                    l_part[((size_t)z * NHEAD + h) * NTP + r] = accL[g][j];
            }
        }
}

// ---------------------------------------------------------------------------
// Reduce kv-splits + per-head normalize + LayerNorm. grid = (NT), 192 thr.
// Each thread owns 4 consecutive dims (float4 loads; same head per quad).
// ---------------------------------------------------------------------------
__global__ __launch_bounds__(192) void reduce_ln_kernel(
    const float* __restrict__ O_part, const float* __restrict__ l_part,
    const float* __restrict__ g, const float* __restrict__ b,
    bf16* __restrict__ out, int nsplit) {
    const int n = blockIdx.x;
    const int tid = threadIdx.x;
    const int d0 = tid * 4;
    const int hh = d0 >> 6;

    float4 o = make_float4(0.f, 0.f, 0.f, 0.f);
    float lv = 0.f;
    for (int s = 0; s < nsplit; ++s) {
        float4 v = *(const float4*)(O_part + ((size_t)s * NT + n) * DMODEL + d0);
        o.x += v.x; o.y += v.y; o.z += v.z; o.w += v.w;
        lv += l_part[((size_t)s * NHEAD + hh) * NTP + n];
    }
    const float inv_l = 1.0f / lv;
    float vals[4] = {o.x * inv_l, o.y * inv_l, o.z * inv_l, o.w * inv_l};

    float s = vals[0] + vals[1] + vals[2] + vals[3];
    float s2 = vals[0] * vals[0] + vals[1] * vals[1] + vals[2] * vals[2] + vals[3] * vals[3];
#pragma unroll
    for (int off = 1; off < 64; off <<= 1) {
        s += __shfl_xor(s, off);
        s2 += __shfl_xor(s2, off);
    }
    __shared__ float ss[3], ss2[3];
    const int wave = tid >> 6, lane = tid & 63;
    if (lane == 0) { ss[wave] = s; ss2[wave] = s2; }
    __syncthreads();
    s = ss[0] + ss[1] + ss[2];
    s2 = ss2[0] + ss2[1] + ss2[2];
    const float mu = s * (1.0f / 768.0f);
    float var = s2 * (1.0f / 768.0f) - mu * mu;
    const float inv = rsqrtf(var + LN_EPS);

    unsigned short pk[4];
#pragma unroll
    for (int i = 0; i < 4; ++i) {
        const int d = d0 + i;
        const float v = (vals[i] - mu) * inv * g[d] + b[d];
        bf16 bb = __float2bfloat16(v);
        pk[i] = *(unsigned short*)&bb;
    }
    *(ushort4*)(out + (size_t)n * DMODEL + d0) = *(ushort4*)pk;
}

// ---------------------------------------------------------------------------
// Output projection v4: gload_lds double-buffered staging, ONE barrier per
// K-step (was 2 __syncthreads + reg round-trip). Slot-linear staging map:
// thread t stages As slots t and t+256 (byte 16*slot; rows t>>2 and
// 64+(t>>2), col (t&3)*8) and Bs slot t. grid = (34, 12). fp32 out.
// ---------------------------------------------------------------------------
__global__ __launch_bounds__(256, 4) void out_kernel(
    const bf16* __restrict__ Lb, const bf16* __restrict__ wo,
    const float* __restrict__ bo_p, const float* __restrict__ bo_d,
    float* __restrict__ out) {
    __shared__ bf16 As[2][128][32];
    __shared__ bf16 Bs[2][64][32];

    const int tid = threadIdx.x;
    const int wave = tid >> 6, lane = tid & 63;
    const int quad = lane >> 4, l16 = lane & 15;
    const int bx = blockIdx.x;
    const int is_det = bx >= 33;
    const int row0 = is_det ? NP : bx * 128;
    const int Mlim = is_det ? NT : NP;
    const int col0 = blockIdx.y * 64;
    const size_t nw = (size_t)DMODEL * DMODEL;
    const bf16* B = wo + (is_det ? nw : 0);
    const float* bias = is_det ? bo_d : bo_p;

    const f32x4 z4 = {0.f, 0.f, 0.f, 0.f};
    f32x4 acc[2][4];
#pragma unroll
    for (int gg = 0; gg < 2; ++gg)
#pragma unroll
        for (int t = 0; t < 4; ++t) acc[gg][t] = z4;

    // slot-linear staging sources: rows sr, 64+sr; col sc
    const int sr = tid >> 2;            // 0..63
    const int sc = (tid & 3) * 8;       // 0,8,16,24
    int ar0 = row0 + sr;       if (ar0 >= Mlim) ar0 = Mlim - 1;
    int ar1 = row0 + 64 + sr;  if (ar1 >= Mlim) ar1 = Mlim - 1;
    const bf16* ap0 = Lb + (size_t)ar0 * DMODEL + sc;
    const bf16* ap1 = Lb + (size_t)ar1 * DMODEL + sc;
    const bf16* bp  = B + (size_t)(col0 + sr) * DMODEL + sc;

    // wave-uniform LDS bases (1 KB per wave per region chunk)
    bf16* asb[2] = {&As[0][0][0] + wave * 512, &As[1][0][0] + wave * 512};
    bf16* bsb[2] = {&Bs[0][0][0] + wave * 512, &Bs[1][0][0] + wave * 512};

    // prologue: stage k0=0 into buffer 0
    {
        gload16(ap0, asb[0]);
        gload16(ap1, asb[0] + 2048);    // As rows 64..127 (byte +4096)
        gload16(bp,  bsb[0]);
    }
    __asm__ volatile("s_waitcnt vmcnt(0)" ::: "memory");
    __builtin_amdgcn_s_barrier();
    __asm__ volatile("" ::: "memory");

    int p = 0;
    for (int k0 = 0; k0 < DMODEL; k0 += 32) {
        if (k0 + 32 < DMODEL) {
            const int kn = k0 + 32;
            gload16(ap0 + kn, asb[p ^ 1]);
            gload16(ap1 + kn, asb[p ^ 1] + 2048);
            gload16(bp + kn,  bsb[p ^ 1]);
        }
        frag8 af[2], bfq[4];
#pragma unroll
        for (int gg = 0; gg < 2; ++gg)
            af[gg] = *(const frag8*)(&As[p][wave * 32 + gg * 16 + l16][quad * 8]);
#pragma unroll
        for (int t = 0; t < 4; ++t)
            bfq[t] = *(const frag8*)(&Bs[p][t * 16 + l16][quad * 8]);
#pragma unroll
        for (int gg = 0; gg < 2; ++gg)
#pragma unroll
            for (int t = 0; t < 4; ++t)
                acc[gg][t] = __builtin_amdgcn_mfma_f32_16x16x32_bf16(af[gg], bfq[t], acc[gg][t], 0, 0, 0);
        // single barrier: next-step stage writes landed; all waves done with p
        __asm__ volatile("s_waitcnt vmcnt(0)" ::: "memory");
        __builtin_amdgcn_s_barrier();
        __asm__ volatile("" ::: "memory");
        p ^= 1;
    }

#pragma unroll
    for (int gg = 0; gg < 2; ++gg) {
        const int rbase = row0 + wave * 32 + gg * 16 + quad * 4;
#pragma unroll
        for (int t = 0; t < 4; ++t) {
            const int c = col0 + t * 16 + l16;
            const float bv = bias[c];
#pragma unroll
            for (int j = 0; j < 4; ++j) {
                const int r = rbase + j;
                if (r < Mlim) out[(size_t)r * DMODEL + c] = acc[gg][t][j] + bv;
            }
        }
    }
}

// ---------------------------------------------------------------------------
extern "C" void kernel_launch(void* const* d_in, const int* in_sizes, int n_in,
                              void* d_out, int out_size, void* d_ws, size_t ws_size,
                              hipStream_t stream) {
    const float* x    = (const float*)d_in[0];
    const float* wq_p = (const float*)d_in[1];
    const float* wk_p = (const float*)d_in[2];
    const float* wv_p = (const float*)d_in[3];
    const float* wq_d = (const float*)d_in[4];
    const float* wk_d = (const float*)d_in[5];
    const float* wv_d = (const float*)d_in[6];
    const float* bq_p = (const float*)d_in[7];
    const float* bv_p = (const float*)d_in[8];
    const float* bq_d = (const float*)d_in[9];
    const float* bv_d = (const float*)d_in[10];
    const float* ln_g = (const float*)d_in[11];
    const float* ln_b = (const float*)d_in[12];
    const float* wo_p = (const float*)d_in[13];
    const float* bo_p = (const float*)d_in[14];
    const float* wo_d = (const float*)d_in[15];
    const float* bo_d = (const float*)d_in[16];
    float* out = (float*)d_out;

    const size_t nx  = (size_t)NT * DMODEL;       // 3,303,168
    const size_t nsw = (size_t)NHEAD * NCHUNK * CHUNKSZ;  // 3,342,336
    const size_t nw  = (size_t)DMODEL * DMODEL;   // 589,824

    // fixed region
    char* ws = (char*)d_ws;
    bf16* xb   = (bf16*)ws; ws += nx * 2;         // reused as Lb after qkv
    bf16* wqkv = (bf16*)ws; ws += 6 * nw * 2;
    bf16* wob  = (bf16*)ws; ws += 2 * nw * 2;
    bf16* Qb   = (bf16*)ws; ws += nx * 2;
    bf16* Ksw  = (bf16*)ws; ws += nsw * 2;
    bf16* Vsw  = (bf16*)ws; ws += nsw * 2;
    const size_t fixed = (size_t)(ws - (char*)d_ws);

    // per-split region: O_part (fp32 NT x 768) + l_part (fp32 12 x NTP).
    // nsplit capped at 2: halves partial write+read traffic vs 4, and the
    // 816-block attn grid fits one residency fill (no second-pass tail).
    const size_t per_split = nx * 4 + (size_t)NHEAD * NTP * 4;
    int nsplit = 1;
    if (ws_size >= fixed + 2 * per_split) nsplit = 2;
    const int cpb = NCHUNK / nsplit;              // 68 divisible by 1/2

    float* O_part = (float*)ws;
    float* l_part = (float*)(ws + (size_t)nsplit * nx * 4);
    bf16* Lb = xb;   // xb dead after qkv_kernel

    const int total = (int)(nx + 8 * nw);
    cast_all_kernel<<<dim3((total / 4 + 255) / 256), dim3(256), 0, stream>>>(
        x, wq_p, wk_p, wv_p, wq_d, wk_d, wv_d, wo_p, wo_d, xb, (int)nx, (int)nw, total);

    qkv_kernel<<<dim3(68, 12), dim3(256), 0, stream>>>(
        xb, wqkv, bq_p, bq_d, bv_p, bv_d, Qb, Ksw, Vsw);

    attn_kernel<<<dim3(34 * NHEAD * nsplit), dim3(256), 0, stream>>>(
        Qb, Ksw, Vsw, O_part, l_part, cpb);

    reduce_ln_kernel<<<dim3(NT), dim3(192), 0, stream>>>(
        O_part, l_part, ln_g, ln_b, Lb, nsplit);

    out_kernel<<<dim3(34, 12), dim3(256), 0, stream>>>(Lb, wob, bo_p, bo_d, out);
}

// Round 13
// 232.558 us; speedup vs baseline: 1.0011x; 1.0011x over previous
//
#include <hip/hip_runtime.h>
#include <hip/hip_bf16.h>

// Problem constants
#define NT 4301   // total tokens
#define NP 4201   // patch tokens (use *_p weights)
#define NDET 100  // detection tokens (use *_d weights)
#define DMODEL 768
#define NHEAD 12
#define HD 64
#define LN_EPS 1e-5f
#define LOG2E 1.4426950408889634f
#define QSCALE (0.125f * LOG2E)   // attn scale folded with log2(e): softmax in exp2 domain
#define NTP 4352                  // padded token count (34*128 = 68*64)
#define NCHUNK 68                 // ceil(4301/64)
#define FRAGSZ 512                // elems per frag blob: 64 lanes x 8 bf16
#define CHUNKSZ 4096              // elems per (head,chunk): 8 frags x 512

typedef __hip_bfloat16 bf16;
typedef __attribute__((ext_vector_type(4))) float f32x4;
typedef __attribute__((ext_vector_type(8))) short frag8;  // 8 bf16 in 4 VGPRs
typedef __attribute__((ext_vector_type(2))) unsigned int u32x2;

// permlane swap helpers (gfx950). Builtin returns {new_dst, new_src}; both used.
static __device__ __forceinline__ void permlane32_swap(unsigned& a, unsigned& b) {
#if __has_builtin(__builtin_amdgcn_permlane32_swap)
    u32x2 r = __builtin_amdgcn_permlane32_swap(a, b, false, false);
    a = r[0]; b = r[1];
#else
    asm("v_permlane32_swap_b32 %0, %1" : "+v"(a), "+v"(b));
#endif
}
static __device__ __forceinline__ void permlane16_swap(unsigned& a, unsigned& b) {
#if __has_builtin(__builtin_amdgcn_permlane16_swap)
    u32x2 r = __builtin_amdgcn_permlane16_swap(a, b, false, false);
    a = r[0]; b = r[1];
#else
    asm("v_permlane16_swap_b32 %0, %1" : "+v"(a), "+v"(b));
#endif
}

// native exp2 (no OCML guard code); v_exp_f32 handles the full f32 range.
static __device__ __forceinline__ float fast_exp2(float x) {
#if __has_builtin(__builtin_amdgcn_exp2f)
    return __builtin_amdgcn_exp2f(x);
#else
    return __builtin_exp2f(x);
#endif
}

// Pack two f32 -> bf16x2 (a -> low16, b -> high16) in ONE v_perm_b32.
// Truncation (no round-to-nearest): softmax divides sum(P*V) by sum(P), so
// the uniform downward bias ~cancels; saves 2 VALU adds per pair vs
// round-half-up.
static __device__ __forceinline__ unsigned pack_bf16_tr(float a, float b) {
    return __builtin_amdgcn_perm(__builtin_bit_cast(unsigned, b),
                                 __builtin_bit_cast(unsigned, a), 0x07060302u);
}

// async global->LDS, 16B per lane. LDS dest = wave-uniform base + lane*16
// (m104); global src is per-lane.
static __device__ __forceinline__ void gload16(const bf16* g, bf16* l) {
    __builtin_amdgcn_global_load_lds(
        (const __attribute__((address_space(1))) void*)g,
        (__attribute__((address_space(3))) void*)l, 16, 0, 0);
}

// ---------------------------------------------------------------------------
// One fused cast: x + 8 weight matrices fp32->bf16 into contiguous ws region
// ---------------------------------------------------------------------------
__global__ __launch_bounds__(256) void cast_all_kernel(
    const float* __restrict__ x,
    const float* __restrict__ w0, const float* __restrict__ w1,
    const float* __restrict__ w2, const float* __restrict__ w3,
    const float* __restrict__ w4, const float* __restrict__ w5,
    const float* __restrict__ w6, const float* __restrict__ w7,
    bf16* __restrict__ dst, int nx, int nw, int total) {
    int i4 = (blockIdx.x * 256 + threadIdx.x) * 4;
    if (i4 >= total) return;
    const float* s;
    int off;
    if (i4 < nx) {
        s = x; off = i4;
    } else {
        int r = i4 - nx;
        int w = r / nw;
        off = r - w * nw;
        s = w0;
        if (w == 1) s = w1; else if (w == 2) s = w2; else if (w == 3) s = w3;
        else if (w == 4) s = w4; else if (w == 5) s = w5;
        else if (w == 6) s = w6; else if (w == 7) s = w7;
    }
    float4 v = *(const float4*)(s + off);
    bf16 o[4] = {__float2bfloat16(v.x), __float2bfloat16(v.y),
                 __float2bfloat16(v.z), __float2bfloat16(v.w)};
    *(ushort4*)(dst + i4) = *(ushort4*)o;
}

// ---------------------------------------------------------------------------
// Fused QKV v3: gload_lds double-buffered staging, ONE barrier per K-step.
// grid = (68, 12). Outputs: Q*QSCALE row-major; K/V pre-swizzled frag order.
// ---------------------------------------------------------------------------
__global__ __launch_bounds__(256, 4) void qkv_kernel(
    const bf16* __restrict__ xb, const bf16* __restrict__ wbase,
    const float* __restrict__ bq_p, const float* __restrict__ bq_d,
    const float* __restrict__ bv_p, const float* __restrict__ bv_d,
    bf16* __restrict__ Qb, bf16* __restrict__ Ksw, bf16* __restrict__ Vsw) {
    __shared__ bf16 As[2][64][32];
    __shared__ bf16 Bs[2][192][32];   // rows 0-63: wq, 64-127: wk, 128-191: wv

    const int tid = threadIdx.x;
    const int wave = tid >> 6, lane = tid & 63;
    const int quad = lane >> 4, l16 = lane & 15;
    const int bx = blockIdx.x;
    const int h = blockIdx.y;
    const int is_det = bx >= 66;
    const int row0 = is_det ? NP + (bx - 66) * 64 : bx * 64;
    const int Mlim = is_det ? NT : NP;
    const int col0 = h * 64;
    const size_t nw = (size_t)DMODEL * DMODEL;
    const bf16* W = wbase + (is_det ? 3 * nw : 0);

    const f32x4 z4 = {0.f, 0.f, 0.f, 0.f};
    f32x4 acc[4][3];
#pragma unroll
    for (int r4 = 0; r4 < 4; ++r4)
#pragma unroll
        for (int f = 0; f < 3; ++f) acc[r4][f] = z4;

    const int srow = tid >> 2;          // 0..63
    const int scol8 = (tid & 3) * 8;    // 0,8,16,24
    int a_r = row0 + srow;
    if (a_r >= Mlim) a_r = Mlim - 1;
    const bf16* ap = xb + (size_t)a_r * DMODEL + scol8;
    const bf16* bp = W + (size_t)(col0 + srow) * DMODEL + scol8;

    // wave-uniform LDS bases (each wave stages its 1 KB quarter per region)
    bf16* asb[2] = {&As[0][0][0] + wave * 512, &As[1][0][0] + wave * 512};
    bf16* bsb[2] = {&Bs[0][0][0] + wave * 512, &Bs[1][0][0] + wave * 512};

    // prologue: stage k0=0 into buffer 0
    {
        gload16(ap, asb[0]);
        gload16(bp, bsb[0]);
        gload16(bp + nw, bsb[0] + 2048);
        gload16(bp + 2 * nw, bsb[0] + 4096);
    }
    __asm__ volatile("s_waitcnt vmcnt(0)" ::: "memory");
    __builtin_amdgcn_s_barrier();
    __asm__ volatile("" ::: "memory");

    int p = 0;
    for (int k0 = 0; k0 < DMODEL; k0 += 32) {
        if (k0 + 32 < DMODEL) {
            const int kn = k0 + 32;
            gload16(ap + kn, asb[p ^ 1]);
            gload16(bp + kn, bsb[p ^ 1]);
            gload16(bp + nw + kn, bsb[p ^ 1] + 2048);
            gload16(bp + 2 * nw + kn, bsb[p ^ 1] + 4096);
        }
        frag8 af[4], bfr[3];
#pragma unroll
        for (int r4 = 0; r4 < 4; ++r4)
            af[r4] = *(const frag8*)(&As[p][r4 * 16 + l16][quad * 8]);
#pragma unroll
        for (int f = 0; f < 3; ++f)
            bfr[f] = *(const frag8*)(&Bs[p][wave * 48 + f * 16 + l16][quad * 8]);
#pragma unroll
        for (int r4 = 0; r4 < 4; ++r4)
#pragma unroll
            for (int f = 0; f < 3; ++f)
                acc[r4][f] = __builtin_amdgcn_mfma_f32_16x16x32_bf16(af[r4], bfr[f], acc[r4][f], 0, 0, 0);
        // single barrier: next-step stage writes landed; all waves done reading p
        __asm__ volatile("s_waitcnt vmcnt(0)" ::: "memory");
        __builtin_amdgcn_s_barrier();
        __asm__ volatile("" ::: "memory");
        p ^= 1;
    }

    // epilogue: wave w covers logical cols [w*48, w*48+48); 16-col group oc=3w+f
#pragma unroll
    for (int f = 0; f < 3; ++f) {
        const int oc = 3 * wave + f;          // 0..11
        const int opi = oc >> 2;              // 0=Q 1=K 2=V
        const int cin = (oc & 3) * 16 + l16;  // head-dim 0..63
        const int c = col0 + cin;             // global dim
        float bv = 0.f, scale = 1.f;
        if (opi == 0) { bv = (is_det ? bq_d : bq_p)[c]; scale = QSCALE; }
        else if (opi == 2) { bv = (is_det ? bv_d : bv_p)[c]; }
#pragma unroll
        for (int r4 = 0; r4 < 4; ++r4) {
#pragma unroll
            for (int j = 0; j < 4; ++j) {
                const int r = row0 + r4 * 16 + quad * 4 + j;
                if (r >= Mlim) continue;
                const bf16 val = __float2bfloat16((acc[r4][f][j] + bv) * scale);
                if (opi == 0) {
                    Qb[(size_t)r * DMODEL + c] = val;
                } else if (opi == 1) {
                    const int cc = r >> 6, tf = (r >> 4) & 3, ln = r & 15;
                    const int s = cin >> 5, qd = (cin >> 3) & 3, je = cin & 7;
                    Ksw[((size_t)(h * NCHUNK + cc) * 8 + tf * 2 + s) * FRAGSZ +
                        (qd * 16 + ln) * 8 + je] = val;
                } else {
                    const int t = cin >> 4, le = cin & 15;
                    const int cc = r >> 6, rr = r & 63;
                    const int sv = rr >> 5, qv = (rr >> 3) & 3, je = rr & 7;
                    Vsw[((size_t)(h * NCHUNK + cc) * 8 + t * 2 + sv) * FRAGSZ +
                        (qv * 16 + le) * 8 + je] = val;
                }
            }
        }
    }
}

// ---------------------------------------------------------------------------
// Flash attention v16 (R9/R10 best, unchanged): 4-wave/256-thr blocks, 128
// q-rows, 32 KB double-buffered K/V via gload_lds, one barrier per chunk,
// swapped QK^T + in-register P (permlane), truncating pack.
// ---------------------------------------------------------------------------
__global__ __launch_bounds__(256, 4) void attn_kernel(
    const bf16* __restrict__ Q, const bf16* __restrict__ Ksw,
    const bf16* __restrict__ Vsw, float* __restrict__ O_part,
    float* __restrict__ l_part, int cpb) {
    __shared__ bf16 KV[2][16][FRAGSZ];   // [buf][frag: 0-7 K, 8-15 V][lane*8]

    const int tid = threadIdx.x;
    const int wave = tid >> 6, lane = tid & 63;
    const int quad = lane >> 4, l16 = lane & 15;

    // decode (bx, h, z) from 1D id; XCD-chunked when blocks/XCD % 34 == 0
    int bx, h, z;
    {
        const int id = blockIdx.x;
        const int nblk = gridDim.x;
        const int per = nblk >> 3;
        if ((nblk & 7) == 0 && per % 34 == 0) {
            const int ppx = per / 34;                 // (h,z) pairs per XCD
            const int q = id >> 3;
            const int pair = (id & 7) * ppx + q / 34;
            bx = q % 34;
            h = pair % NHEAD; z = pair / NHEAD;
        } else {
            bx = id % 34; h = (id / 34) % NHEAD; z = id / (34 * NHEAD);
        }
    }
    const int qbase = bx * 128;
    const int hoff = h * HD;
    const int c0 = z * cpb, c1 = c0 + cpb;

    frag8 ones;
#pragma unroll
    for (int j = 0; j < 8; ++j) ones[j] = (short)0x3F80;

    // Q fragments for 2 row-groups: rows qbase + wave*32 + g*16 + l16.
    frag8 qf[2][2];
#pragma unroll
    for (int g = 0; g < 2; ++g) {
        int qr = qbase + wave * 32 + g * 16 + l16;
        if (qr >= NT) qr = NT - 1;
#pragma unroll
        for (int s = 0; s < 2; ++s)
            qf[g][s] = *(const frag8*)(Q + (size_t)qr * DMODEL + hoff + s * 32 + quad * 8);
    }

    // staging: wave 0/1 -> K frags 0-3/4-7, wave 2/3 -> V frags 0-3/4-7.
    const bf16* kb0 = Ksw + (size_t)h * NCHUNK * CHUNKSZ + lane * 8;
    const bf16* vb0 = Vsw + (size_t)h * NCHUNK * CHUNKSZ + lane * 8;
    const bf16* sb = (wave < 2) ? kb0 : vb0;
    const int foff = (wave & 1) * 4;      // frag index within K or V blob
    const int fbase = 4 * wave;           // LDS frag row

    const f32x4 z4 = {0.f, 0.f, 0.f, 0.f};
    f32x4 accO[2][4], accL[2];
#pragma unroll
    for (int g = 0; g < 2; ++g) {
        accL[g] = z4;
#pragma unroll
        for (int t = 0; t < 4; ++t) accO[g][t] = z4;
    }

    // prologue: stage chunk c0 into buffer 0, drain, sync
    {
        const bf16* s = sb + (size_t)c0 * CHUNKSZ + foff * FRAGSZ;
#pragma unroll
        for (int i = 0; i < 4; ++i)
            gload16(s + i * FRAGSZ, &KV[0][fbase + i][0]);
    }
    __asm__ volatile("s_waitcnt vmcnt(0)" ::: "memory");
    __builtin_amdgcn_s_barrier();
    __asm__ volatile("" ::: "memory");

    int p = 0;
    for (int c = c0; c < c1; ++c) {
        // stage next chunk into the other buffer; flight hidden under compute
        if (c + 1 < c1) {
            const bf16* s = sb + (size_t)(c + 1) * CHUNKSZ + foff * FRAGSZ;
#pragma unroll
            for (int i = 0; i < 4; ++i)
                gload16(s + i * FRAGSZ, &KV[p ^ 1][fbase + i][0]);
        }

        // S^T = K @ Q^T; kf read per-t at point of use (8 live K VGPRs)
        f32x4 S[2][4];
#pragma unroll
        for (int t = 0; t < 4; ++t) {
            const frag8 k0 = *(const frag8*)(&KV[p][t * 2 + 0][lane * 8]);
            const frag8 k1 = *(const frag8*)(&KV[p][t * 2 + 1][lane * 8]);
#pragma unroll
            for (int g = 0; g < 2; ++g) {
                f32x4 s0 = __builtin_amdgcn_mfma_f32_16x16x32_bf16(k0, qf[g][0], z4, 0, 0, 0);
                S[g][t]  = __builtin_amdgcn_mfma_f32_16x16x32_bf16(k1, qf[g][1], s0, 0, 0, 0);
            }
        }
        if (c == NCHUNK - 1) {
            const int kb = c * 64 + quad * 4;   // k row index base for this lane
#pragma unroll
            for (int t = 0; t < 4; ++t)
#pragma unroll
                for (int j = 0; j < 4; ++j)
                    if (kb + t * 16 + j >= NT) {
                        S[0][t][j] = -1e30f;
                        S[1][t][j] = -1e30f;
                    }
        }

        // softmax: exp2 -> 1-op truncating pack -> permlane assembly
        frag8 pf[2][2];   // [g][s]
#pragma unroll
        for (int g = 0; g < 2; ++g) {
            unsigned lo[4], hi[4];
#pragma unroll
            for (int t = 0; t < 4; ++t) {
                lo[t] = pack_bf16_tr(fast_exp2(S[g][t][0]), fast_exp2(S[g][t][1]));
                hi[t] = pack_bf16_tr(fast_exp2(S[g][t][2]), fast_exp2(S[g][t][3]));
            }
#pragma unroll
            for (int s = 0; s < 2; ++s) {
                unsigned A = lo[2 * s], B = hi[2 * s];
                unsigned C = lo[2 * s + 1], D = hi[2 * s + 1];
                permlane32_swap(A, C);
                permlane32_swap(B, D);
                permlane16_swap(A, C);
                permlane16_swap(B, D);
                union { unsigned u[4]; frag8 f; } pu;
                pu.u[0] = A; pu.u[1] = B; pu.u[2] = C; pu.u[3] = D;
                pf[g][s] = pu.f;
                accL[g] = __builtin_amdgcn_mfma_f32_16x16x32_bf16(pf[g][s], ones, accL[g], 0, 0, 0);
            }
        }

        // O += P @ V ; vf read per (s,t), shared across both row-groups
#pragma unroll
        for (int s = 0; s < 2; ++s)
#pragma unroll
            for (int t = 0; t < 4; ++t) {
                const frag8 v = *(const frag8*)(&KV[p][8 + t * 2 + s][lane * 8]);
#pragma unroll
                for (int g = 0; g < 2; ++g)
                    accO[g][t] = __builtin_amdgcn_mfma_f32_16x16x32_bf16(pf[g][s], v, accO[g][t], 0, 0, 0);
            }

        // single barrier per chunk: stage writes landed (vmcnt 0, hidden
        // under the compute above) and every wave is done reading buf p.
        __asm__ volatile("s_waitcnt vmcnt(0)" ::: "memory");
        __builtin_amdgcn_s_barrier();
        __asm__ volatile("" ::: "memory");
        p ^= 1;
    }

    // write fp32 partials
    float* Op = O_part + (size_t)z * NT * DMODEL;
#pragma unroll
    for (int g = 0; g < 2; ++g)
#pragma unroll
        for (int j = 0; j < 4; ++j) {
            const int r = qbase + wave * 32 + g * 16 + quad * 4 + j;
            if (r < NT) {
#pragma unroll
                for (int t = 0; t < 4; ++t)
                    Op[(size_t)r * DMODEL + hoff + t * 16 + l16] = accO[g][t][j];
                if (l16 == 0)
                    l_part[((size_t)z * NHEAD + h) * NTP + r] = accL[g][j];
            }
        }
}

// ---------------------------------------------------------------------------
// Reduce kv-splits + per-head normalize + LayerNorm. grid = (NT), 192 thr.
// Each thread owns 4 consecutive dims (float4 loads; same head per quad).
// ---------------------------------------------------------------------------
__global__ __launch_bounds__(192) void reduce_ln_kernel(
    const float* __restrict__ O_part, const float* __restrict__ l_part,
    const float* __restrict__ g, const float* __restrict__ b,
    bf16* __restrict__ out, int nsplit) {
    const int n = blockIdx.x;
    const int tid = threadIdx.x;
    const int d0 = tid * 4;
    const int hh = d0 >> 6;

    float4 o = make_float4(0.f, 0.f, 0.f, 0.f);
    float lv = 0.f;
    for (int s = 0; s < nsplit; ++s) {
        float4 v = *(const float4*)(O_part + ((size_t)s * NT + n) * DMODEL + d0);
        o.x += v.x; o.y += v.y; o.z += v.z; o.w += v.w;
        lv += l_part[((size_t)s * NHEAD + hh) * NTP + n];
    }
    const float inv_l = 1.0f / lv;
    float vals[4] = {o.x * inv_l, o.y * inv_l, o.z * inv_l, o.w * inv_l};

    float s = vals[0] + vals[1] + vals[2] + vals[3];
    float s2 = vals[0] * vals[0] + vals[1] * vals[1] + vals[2] * vals[2] + vals[3] * vals[3];
#pragma unroll
    for (int off = 1; off < 64; off <<= 1) {
        s += __shfl_xor(s, off);
        s2 += __shfl_xor(s2, off);
    }
    __shared__ float ss[3], ss2[3];
    const int wave = tid >> 6, lane = tid & 63;
    if (lane == 0) { ss[wave] = s; ss2[wave] = s2; }
    __syncthreads();
    s = ss[0] + ss[1] + ss[2];
    s2 = ss2[0] + ss2[1] + ss2[2];
    const float mu = s * (1.0f / 768.0f);
    float var = s2 * (1.0f / 768.0f) - mu * mu;
    const float inv = rsqrtf(var + LN_EPS);

    unsigned short pk[4];
#pragma unroll
    for (int i = 0; i < 4; ++i) {
        const int d = d0 + i;
        const float v = (vals[i] - mu) * inv * g[d] + b[d];
        bf16 bb = __float2bfloat16(v);
        pk[i] = *(unsigned short*)&bb;
    }
    *(ushort4*)(out + (size_t)n * DMODEL + d0) = *(ushort4*)pk;
}

// ---------------------------------------------------------------------------
// Output projection v4: gload_lds double-buffered staging, ONE barrier per
// K-step. Slot-linear staging map: thread t stages As slots t and t+256
// (byte 16*slot; rows t>>2 and 64+(t>>2), col (t&3)*8) and Bs slot t.
// grid = (34, 12). fp32 out.
// ---------------------------------------------------------------------------
__global__ __launch_bounds__(256, 4) void out_kernel(
    const bf16* __restrict__ Lb, const bf16* __restrict__ wo,
    const float* __restrict__ bo_p, const float* __restrict__ bo_d,
    float* __restrict__ out) {
    __shared__ bf16 As[2][128][32];
    __shared__ bf16 Bs[2][64][32];

    const int tid = threadIdx.x;
    const int wave = tid >> 6, lane = tid & 63;
    const int quad = lane >> 4, l16 = lane & 15;
    const int bx = blockIdx.x;
    const int is_det = bx >= 33;
    const int row0 = is_det ? NP : bx * 128;
    const int Mlim = is_det ? NT : NP;
    const int col0 = blockIdx.y * 64;
    const size_t nw = (size_t)DMODEL * DMODEL;
    const bf16* B = wo + (is_det ? nw : 0);
    const float* bias = is_det ? bo_d : bo_p;

    const f32x4 z4 = {0.f, 0.f, 0.f, 0.f};
    f32x4 acc[2][4];
#pragma unroll
    for (int gg = 0; gg < 2; ++gg)
#pragma unroll
        for (int t = 0; t < 4; ++t) acc[gg][t] = z4;

    // slot-linear staging sources: rows sr, 64+sr; col sc
    const int sr = tid >> 2;            // 0..63
    const int sc = (tid & 3) * 8;       // 0,8,16,24
    int ar0 = row0 + sr;       if (ar0 >= Mlim) ar0 = Mlim - 1;
    int ar1 = row0 + 64 + sr;  if (ar1 >= Mlim) ar1 = Mlim - 1;
    const bf16* ap0 = Lb + (size_t)ar0 * DMODEL + sc;
    const bf16* ap1 = Lb + (size_t)ar1 * DMODEL + sc;
    const bf16* bp  = B + (size_t)(col0 + sr) * DMODEL + sc;

    // wave-uniform LDS bases (1 KB per wave per region chunk)
    bf16* asb[2] = {&As[0][0][0] + wave * 512, &As[1][0][0] + wave * 512};
    bf16* bsb[2] = {&Bs[0][0][0] + wave * 512, &Bs[1][0][0] + wave * 512};

    // prologue: stage k0=0 into buffer 0
    {
        gload16(ap0, asb[0]);
        gload16(ap1, asb[0] + 2048);    // As rows 64..127 (byte +4096)
        gload16(bp,  bsb[0]);
    }
    __asm__ volatile("s_waitcnt vmcnt(0)" ::: "memory");
    __builtin_amdgcn_s_barrier();
    __asm__ volatile("" ::: "memory");

    int p = 0;
    for (int k0 = 0; k0 < DMODEL; k0 += 32) {
        if (k0 + 32 < DMODEL) {
            const int kn = k0 + 32;
            gload16(ap0 + kn, asb[p ^ 1]);
            gload16(ap1 + kn, asb[p ^ 1] + 2048);
            gload16(bp + kn,  bsb[p ^ 1]);
        }
        frag8 af[2], bfq[4];
#pragma unroll
        for (int gg = 0; gg < 2; ++gg)
            af[gg] = *(const frag8*)(&As[p][wave * 32 + gg * 16 + l16][quad * 8]);
#pragma unroll
        for (int t = 0; t < 4; ++t)
            bfq[t] = *(const frag8*)(&Bs[p][t * 16 + l16][quad * 8]);
#pragma unroll
        for (int gg = 0; gg < 2; ++gg)
#pragma unroll
            for (int t = 0; t < 4; ++t)
                acc[gg][t] = __builtin_amdgcn_mfma_f32_16x16x32_bf16(af[gg], bfq[t], acc[gg][t], 0, 0, 0);
        // single barrier: next-step stage writes landed; all waves done with p
        __asm__ volatile("s_waitcnt vmcnt(0)" ::: "memory");
        __builtin_amdgcn_s_barrier();
        __asm__ volatile("" ::: "memory");
        p ^= 1;
    }

#pragma unroll
    for (int gg = 0; gg < 2; ++gg) {
        const int rbase = row0 + wave * 32 + gg * 16 + quad * 4;
#pragma unroll
        for (int t = 0; t < 4; ++t) {
            const int c = col0 + t * 16 + l16;
            const float bv = bias[c];
#pragma unroll
            for (int j = 0; j < 4; ++j) {
                const int r = rbase + j;
                if (r < Mlim) out[(size_t)r * DMODEL + c] = acc[gg][t][j] + bv;
            }
        }
    }
}

// ---------------------------------------------------------------------------
extern "C" void kernel_launch(void* const* d_in, const int* in_sizes, int n_in,
                              void* d_out, int out_size, void* d_ws, size_t ws_size,
                              hipStream_t stream) {
    const float* x    = (const float*)d_in[0];
    const float* wq_p = (const float*)d_in[1];
    const float* wk_p = (const float*)d_in[2];
    const float* wv_p = (const float*)d_in[3];
    const float* wq_d = (const float*)d_in[4];
    const float* wk_d = (const float*)d_in[5];
    const float* wv_d = (const float*)d_in[6];
    const float* bq_p = (const float*)d_in[7];
    const float* bv_p = (const float*)d_in[8];
    const float* bq_d = (const float*)d_in[9];
    const float* bv_d = (const float*)d_in[10];
    const float* ln_g = (const float*)d_in[11];
    const float* ln_b = (const float*)d_in[12];
    const float* wo_p = (const float*)d_in[13];
    const float* bo_p = (const float*)d_in[14];
    const float* wo_d = (const float*)d_in[15];
    const float* bo_d = (const float*)d_in[16];
    float* out = (float*)d_out;

    const size_t nx  = (size_t)NT * DMODEL;       // 3,303,168
    const size_t nsw = (size_t)NHEAD * NCHUNK * CHUNKSZ;  // 3,342,336
    const size_t nw  = (size_t)DMODEL * DMODEL;   // 589,824

    // fixed region
    char* ws = (char*)d_ws;
    bf16* xb   = (bf16*)ws; ws += nx * 2;         // reused as Lb after qkv
    bf16* wqkv = (bf16*)ws; ws += 6 * nw * 2;
    bf16* wob  = (bf16*)ws; ws += 2 * nw * 2;
    bf16* Qb   = (bf16*)ws; ws += nx * 2;
    bf16* Ksw  = (bf16*)ws; ws += nsw * 2;
    bf16* Vsw  = (bf16*)ws; ws += nsw * 2;
    const size_t fixed = (size_t)(ws - (char*)d_ws);

    // per-split region: O_part (fp32 NT x 768) + l_part (fp32 12 x NTP).
    // nsplit=4 preferred: 1632-block attn grid = 6.4 blocks/CU gives fine
    // tail granularity (nsplit=2's 816 blocks = 3.2/CU cost +5.5us from
    // coarse load imbalance, R12 measured).
    const size_t per_split = nx * 4 + (size_t)NHEAD * NTP * 4;
    int nsplit = 1;
    if (ws_size >= fixed + 4 * per_split) nsplit = 4;
    else if (ws_size >= fixed + 2 * per_split) nsplit = 2;
    const int cpb = NCHUNK / nsplit;              // 68 divisible by 1/2/4

    float* O_part = (float*)ws;
    float* l_part = (float*)(ws + (size_t)nsplit * nx * 4);
    bf16* Lb = xb;   // xb dead after qkv_kernel

    const int total = (int)(nx + 8 * nw);
    cast_all_kernel<<<dim3((total / 4 + 255) / 256), dim3(256), 0, stream>>>(
        x, wq_p, wk_p, wv_p, wq_d, wk_d, wv_d, wo_p, wo_d, xb, (int)nx, (int)nw, total);

    qkv_kernel<<<dim3(68, 12), dim3(256), 0, stream>>>(
        xb, wqkv, bq_p, bq_d, bv_p, bv_d, Qb, Ksw, Vsw);

    attn_kernel<<<dim3(34 * NHEAD * nsplit), dim3(256), 0, stream>>>(
        Qb, Ksw, Vsw, O_part, l_part, cpb);

    reduce_ln_kernel<<<dim3(NT), dim3(192), 0, stream>>>(
        O_part, l_part, ln_g, ln_b, Lb, nsplit);

    out_kernel<<<dim3(34, 12), dim3(256), 0, stream>>>(Lb, wob, bo_p, bo_d, out);
}

// Round 14
// 226.817 us; speedup vs baseline: 1.0264x; 1.0253x over previous
//
#include <hip/hip_runtime.h>
#include <hip/hip_bf16.h>

// Problem constants
#define NT 4301   // total tokens
#define NP 4201   // patch tokens (use *_p weights)
#define NDET 100  // detection tokens (use *_d weights)
#define DMODEL 768
#define NHEAD 12
#define HD 64
#define LN_EPS 1e-5f
#define LOG2E 1.4426950408889634f
#define QSCALE (0.125f * LOG2E)   // attn scale folded with log2(e): softmax in exp2 domain
#define NTP 4352                  // padded token count (34*128 = 68*64)
#define NCHUNK 68                 // ceil(4301/64)
#define FRAGSZ 512                // elems per frag blob: 64 lanes x 8 bf16
#define CHUNKSZ 4096              // elems per (head,chunk): 8 frags x 512

typedef __hip_bfloat16 bf16;
typedef __attribute__((ext_vector_type(4))) float f32x4;
typedef __attribute__((ext_vector_type(8))) short frag8;  // 8 bf16 in 4 VGPRs
typedef __attribute__((ext_vector_type(2))) unsigned int u32x2;

// permlane swap helpers (gfx950). Builtin returns {new_dst, new_src}; both used.
static __device__ __forceinline__ void permlane32_swap(unsigned& a, unsigned& b) {
#if __has_builtin(__builtin_amdgcn_permlane32_swap)
    u32x2 r = __builtin_amdgcn_permlane32_swap(a, b, false, false);
    a = r[0]; b = r[1];
#else
    asm("v_permlane32_swap_b32 %0, %1" : "+v"(a), "+v"(b));
#endif
}
static __device__ __forceinline__ void permlane16_swap(unsigned& a, unsigned& b) {
#if __has_builtin(__builtin_amdgcn_permlane16_swap)
    u32x2 r = __builtin_amdgcn_permlane16_swap(a, b, false, false);
    a = r[0]; b = r[1];
#else
    asm("v_permlane16_swap_b32 %0, %1" : "+v"(a), "+v"(b));
#endif
}

// native exp2 (no OCML guard code); v_exp_f32 handles the full f32 range.
static __device__ __forceinline__ float fast_exp2(float x) {
#if __has_builtin(__builtin_amdgcn_exp2f)
    return __builtin_amdgcn_exp2f(x);
#else
    return __builtin_exp2f(x);
#endif
}

// Pack two f32 -> bf16x2 (a -> low16, b -> high16) in ONE v_perm_b32.
// Truncation (no round-to-nearest): softmax divides sum(P*V) by sum(P), so
// the uniform downward bias ~cancels; saves 2 VALU adds per pair vs
// round-half-up.
static __device__ __forceinline__ unsigned pack_bf16_tr(float a, float b) {
    return __builtin_amdgcn_perm(__builtin_bit_cast(unsigned, b),
                                 __builtin_bit_cast(unsigned, a), 0x07060302u);
}

// bf16 -> f32 (exact)
static __device__ __forceinline__ float bf16_to_f32(unsigned short u) {
    return __builtin_bit_cast(float, (unsigned)u << 16);
}

// async global->LDS, 16B per lane. LDS dest = wave-uniform base + lane*16
// (m104); global src is per-lane.
static __device__ __forceinline__ void gload16(const bf16* g, bf16* l) {
    __builtin_amdgcn_global_load_lds(
        (const __attribute__((address_space(1))) void*)g,
        (__attribute__((address_space(3))) void*)l, 16, 0, 0);
}

// ---------------------------------------------------------------------------
// One fused cast: x + 8 weight matrices fp32->bf16 into contiguous ws region
// ---------------------------------------------------------------------------
__global__ __launch_bounds__(256) void cast_all_kernel(
    const float* __restrict__ x,
    const float* __restrict__ w0, const float* __restrict__ w1,
    const float* __restrict__ w2, const float* __restrict__ w3,
    const float* __restrict__ w4, const float* __restrict__ w5,
    const float* __restrict__ w6, const float* __restrict__ w7,
    bf16* __restrict__ dst, int nx, int nw, int total) {
    int i4 = (blockIdx.x * 256 + threadIdx.x) * 4;
    if (i4 >= total) return;
    const float* s;
    int off;
    if (i4 < nx) {
        s = x; off = i4;
    } else {
        int r = i4 - nx;
        int w = r / nw;
        off = r - w * nw;
        s = w0;
        if (w == 1) s = w1; else if (w == 2) s = w2; else if (w == 3) s = w3;
        else if (w == 4) s = w4; else if (w == 5) s = w5;
        else if (w == 6) s = w6; else if (w == 7) s = w7;
    }
    float4 v = *(const float4*)(s + off);
    bf16 o[4] = {__float2bfloat16(v.x), __float2bfloat16(v.y),
                 __float2bfloat16(v.z), __float2bfloat16(v.w)};
    *(ushort4*)(dst + i4) = *(ushort4*)o;
}

// ---------------------------------------------------------------------------
// Fused QKV v3: gload_lds double-buffered staging, ONE barrier per K-step.
// grid = (68, 12). Outputs: Q*QSCALE row-major; K/V pre-swizzled frag order.
// ---------------------------------------------------------------------------
__global__ __launch_bounds__(256, 4) void qkv_kernel(
    const bf16* __restrict__ xb, const bf16* __restrict__ wbase,
    const float* __restrict__ bq_p, const float* __restrict__ bq_d,
    const float* __restrict__ bv_p, const float* __restrict__ bv_d,
    bf16* __restrict__ Qb, bf16* __restrict__ Ksw, bf16* __restrict__ Vsw) {
    __shared__ bf16 As[2][64][32];
    __shared__ bf16 Bs[2][192][32];   // rows 0-63: wq, 64-127: wk, 128-191: wv

    const int tid = threadIdx.x;
    const int wave = tid >> 6, lane = tid & 63;
    const int quad = lane >> 4, l16 = lane & 15;
    const int bx = blockIdx.x;
    const int h = blockIdx.y;
    const int is_det = bx >= 66;
    const int row0 = is_det ? NP + (bx - 66) * 64 : bx * 64;
    const int Mlim = is_det ? NT : NP;
    const int col0 = h * 64;
    const size_t nw = (size_t)DMODEL * DMODEL;
    const bf16* W = wbase + (is_det ? 3 * nw : 0);

    const f32x4 z4 = {0.f, 0.f, 0.f, 0.f};
    f32x4 acc[4][3];
#pragma unroll
    for (int r4 = 0; r4 < 4; ++r4)
#pragma unroll
        for (int f = 0; f < 3; ++f) acc[r4][f] = z4;

    const int srow = tid >> 2;          // 0..63
    const int scol8 = (tid & 3) * 8;    // 0,8,16,24
    int a_r = row0 + srow;
    if (a_r >= Mlim) a_r = Mlim - 1;
    const bf16* ap = xb + (size_t)a_r * DMODEL + scol8;
    const bf16* bp = W + (size_t)(col0 + srow) * DMODEL + scol8;

    // wave-uniform LDS bases (each wave stages its 1 KB quarter per region)
    bf16* asb[2] = {&As[0][0][0] + wave * 512, &As[1][0][0] + wave * 512};
    bf16* bsb[2] = {&Bs[0][0][0] + wave * 512, &Bs[1][0][0] + wave * 512};

    // prologue: stage k0=0 into buffer 0
    {
        gload16(ap, asb[0]);
        gload16(bp, bsb[0]);
        gload16(bp + nw, bsb[0] + 2048);
        gload16(bp + 2 * nw, bsb[0] + 4096);
    }
    __asm__ volatile("s_waitcnt vmcnt(0)" ::: "memory");
    __builtin_amdgcn_s_barrier();
    __asm__ volatile("" ::: "memory");

    int p = 0;
    for (int k0 = 0; k0 < DMODEL; k0 += 32) {
        if (k0 + 32 < DMODEL) {
            const int kn = k0 + 32;
            gload16(ap + kn, asb[p ^ 1]);
            gload16(bp + kn, bsb[p ^ 1]);
            gload16(bp + nw + kn, bsb[p ^ 1] + 2048);
            gload16(bp + 2 * nw + kn, bsb[p ^ 1] + 4096);
        }
        frag8 af[4], bfr[3];
#pragma unroll
        for (int r4 = 0; r4 < 4; ++r4)
            af[r4] = *(const frag8*)(&As[p][r4 * 16 + l16][quad * 8]);
#pragma unroll
        for (int f = 0; f < 3; ++f)
            bfr[f] = *(const frag8*)(&Bs[p][wave * 48 + f * 16 + l16][quad * 8]);
#pragma unroll
        for (int r4 = 0; r4 < 4; ++r4)
#pragma unroll
            for (int f = 0; f < 3; ++f)
                acc[r4][f] = __builtin_amdgcn_mfma_f32_16x16x32_bf16(af[r4], bfr[f], acc[r4][f], 0, 0, 0);
        // single barrier: next-step stage writes landed; all waves done reading p
        __asm__ volatile("s_waitcnt vmcnt(0)" ::: "memory");
        __builtin_amdgcn_s_barrier();
        __asm__ volatile("" ::: "memory");
        p ^= 1;
    }

    // epilogue: wave w covers logical cols [w*48, w*48+48); 16-col group oc=3w+f
#pragma unroll
    for (int f = 0; f < 3; ++f) {
        const int oc = 3 * wave + f;          // 0..11
        const int opi = oc >> 2;              // 0=Q 1=K 2=V
        const int cin = (oc & 3) * 16 + l16;  // head-dim 0..63
        const int c = col0 + cin;             // global dim
        float bv = 0.f, scale = 1.f;
        if (opi == 0) { bv = (is_det ? bq_d : bq_p)[c]; scale = QSCALE; }
        else if (opi == 2) { bv = (is_det ? bv_d : bv_p)[c]; }
#pragma unroll
        for (int r4 = 0; r4 < 4; ++r4) {
#pragma unroll
            for (int j = 0; j < 4; ++j) {
                const int r = row0 + r4 * 16 + quad * 4 + j;
                if (r >= Mlim) continue;
                const bf16 val = __float2bfloat16((acc[r4][f][j] + bv) * scale);
                if (opi == 0) {
                    Qb[(size_t)r * DMODEL + c] = val;
                } else if (opi == 1) {
                    const int cc = r >> 6, tf = (r >> 4) & 3, ln = r & 15;
                    const int s = cin >> 5, qd = (cin >> 3) & 3, je = cin & 7;
                    Ksw[((size_t)(h * NCHUNK + cc) * 8 + tf * 2 + s) * FRAGSZ +
                        (qd * 16 + ln) * 8 + je] = val;
                } else {
                    const int t = cin >> 4, le = cin & 15;
                    const int cc = r >> 6, rr = r & 63;
                    const int sv = rr >> 5, qv = (rr >> 3) & 3, je = rr & 7;
                    Vsw[((size_t)(h * NCHUNK + cc) * 8 + t * 2 + sv) * FRAGSZ +
                        (qv * 16 + le) * 8 + je] = val;
                }
            }
        }
    }
}

// ---------------------------------------------------------------------------
// Flash attention v17: v16 structure; partials now written in bf16 (halves
// partial-store traffic; error ~ulp(17)/l ~ 1e-5 pre-LN, negligible).
// ---------------------------------------------------------------------------
__global__ __launch_bounds__(256, 4) void attn_kernel(
    const bf16* __restrict__ Q, const bf16* __restrict__ Ksw,
    const bf16* __restrict__ Vsw, bf16* __restrict__ O_part,
    float* __restrict__ l_part, int cpb) {
    __shared__ bf16 KV[2][16][FRAGSZ];   // [buf][frag: 0-7 K, 8-15 V][lane*8]

    const int tid = threadIdx.x;
    const int wave = tid >> 6, lane = tid & 63;
    const int quad = lane >> 4, l16 = lane & 15;

    // decode (bx, h, z) from 1D id; XCD-chunked when blocks/XCD % 34 == 0
    int bx, h, z;
    {
        const int id = blockIdx.x;
        const int nblk = gridDim.x;
        const int per = nblk >> 3;
        if ((nblk & 7) == 0 && per % 34 == 0) {
            const int ppx = per / 34;                 // (h,z) pairs per XCD
            const int q = id >> 3;
            const int pair = (id & 7) * ppx + q / 34;
            bx = q % 34;
            h = pair % NHEAD; z = pair / NHEAD;
        } else {
            bx = id % 34; h = (id / 34) % NHEAD; z = id / (34 * NHEAD);
        }
    }
    const int qbase = bx * 128;
    const int hoff = h * HD;
    const int c0 = z * cpb, c1 = c0 + cpb;

    frag8 ones;
#pragma unroll
    for (int j = 0; j < 8; ++j) ones[j] = (short)0x3F80;

    // Q fragments for 2 row-groups: rows qbase + wave*32 + g*16 + l16.
    frag8 qf[2][2];
#pragma unroll
    for (int g = 0; g < 2; ++g) {
        int qr = qbase + wave * 32 + g * 16 + l16;
        if (qr >= NT) qr = NT - 1;
#pragma unroll
        for (int s = 0; s < 2; ++s)
            qf[g][s] = *(const frag8*)(Q + (size_t)qr * DMODEL + hoff + s * 32 + quad * 8);
    }

    // staging: wave 0/1 -> K frags 0-3/4-7, wave 2/3 -> V frags 0-3/4-7.
    const bf16* kb0 = Ksw + (size_t)h * NCHUNK * CHUNKSZ + lane * 8;
    const bf16* vb0 = Vsw + (size_t)h * NCHUNK * CHUNKSZ + lane * 8;
    const bf16* sb = (wave < 2) ? kb0 : vb0;
    const int foff = (wave & 1) * 4;      // frag index within K or V blob
    const int fbase = 4 * wave;           // LDS frag row

    const f32x4 z4 = {0.f, 0.f, 0.f, 0.f};
    f32x4 accO[2][4], accL[2];
#pragma unroll
    for (int g = 0; g < 2; ++g) {
        accL[g] = z4;
#pragma unroll
        for (int t = 0; t < 4; ++t) accO[g][t] = z4;
    }

    // prologue: stage chunk c0 into buffer 0, drain, sync
    {
        const bf16* s = sb + (size_t)c0 * CHUNKSZ + foff * FRAGSZ;
#pragma unroll
        for (int i = 0; i < 4; ++i)
            gload16(s + i * FRAGSZ, &KV[0][fbase + i][0]);
    }
    __asm__ volatile("s_waitcnt vmcnt(0)" ::: "memory");
    __builtin_amdgcn_s_barrier();
    __asm__ volatile("" ::: "memory");

    int p = 0;
    for (int c = c0; c < c1; ++c) {
        // stage next chunk into the other buffer; flight hidden under compute
        if (c + 1 < c1) {
            const bf16* s = sb + (size_t)(c + 1) * CHUNKSZ + foff * FRAGSZ;
#pragma unroll
            for (int i = 0; i < 4; ++i)
                gload16(s + i * FRAGSZ, &KV[p ^ 1][fbase + i][0]);
        }

        // S^T = K @ Q^T; kf read per-t at point of use (8 live K VGPRs)
        f32x4 S[2][4];
#pragma unroll
        for (int t = 0; t < 4; ++t) {
            const frag8 k0 = *(const frag8*)(&KV[p][t * 2 + 0][lane * 8]);
            const frag8 k1 = *(const frag8*)(&KV[p][t * 2 + 1][lane * 8]);
#pragma unroll
            for (int g = 0; g < 2; ++g) {
                f32x4 s0 = __builtin_amdgcn_mfma_f32_16x16x32_bf16(k0, qf[g][0], z4, 0, 0, 0);
                S[g][t]  = __builtin_amdgcn_mfma_f32_16x16x32_bf16(k1, qf[g][1], s0, 0, 0, 0);
            }
        }
        if (c == NCHUNK - 1) {
            const int kb = c * 64 + quad * 4;   // k row index base for this lane
#pragma unroll
            for (int t = 0; t < 4; ++t)
#pragma unroll
                for (int j = 0; j < 4; ++j)
                    if (kb + t * 16 + j >= NT) {
                        S[0][t][j] = -1e30f;
                        S[1][t][j] = -1e30f;
                    }
        }

        // softmax: exp2 -> 1-op truncating pack -> permlane assembly
        frag8 pf[2][2];   // [g][s]
#pragma unroll
        for (int g = 0; g < 2; ++g) {
            unsigned lo[4], hi[4];
#pragma unroll
            for (int t = 0; t < 4; ++t) {
                lo[t] = pack_bf16_tr(fast_exp2(S[g][t][0]), fast_exp2(S[g][t][1]));
                hi[t] = pack_bf16_tr(fast_exp2(S[g][t][2]), fast_exp2(S[g][t][3]));
            }
#pragma unroll
            for (int s = 0; s < 2; ++s) {
                unsigned A = lo[2 * s], B = hi[2 * s];
                unsigned C = lo[2 * s + 1], D = hi[2 * s + 1];
                permlane32_swap(A, C);
                permlane32_swap(B, D);
                permlane16_swap(A, C);
                permlane16_swap(B, D);
                union { unsigned u[4]; frag8 f; } pu;
                pu.u[0] = A; pu.u[1] = B; pu.u[2] = C; pu.u[3] = D;
                pf[g][s] = pu.f;
                accL[g] = __builtin_amdgcn_mfma_f32_16x16x32_bf16(pf[g][s], ones, accL[g], 0, 0, 0);
            }
        }

        // O += P @ V ; vf read per (s,t), shared across both row-groups
#pragma unroll
        for (int s = 0; s < 2; ++s)
#pragma unroll
            for (int t = 0; t < 4; ++t) {
                const frag8 v = *(const frag8*)(&KV[p][8 + t * 2 + s][lane * 8]);
#pragma unroll
                for (int g = 0; g < 2; ++g)
                    accO[g][t] = __builtin_amdgcn_mfma_f32_16x16x32_bf16(pf[g][s], v, accO[g][t], 0, 0, 0);
            }

        // single barrier per chunk: stage writes landed (vmcnt 0, hidden
        // under the compute above) and every wave is done reading buf p.
        __asm__ volatile("s_waitcnt vmcnt(0)" ::: "memory");
        __builtin_amdgcn_s_barrier();
        __asm__ volatile("" ::: "memory");
        p ^= 1;
    }

    // write bf16 partials (RNE convert; epilogue-only cost)
    bf16* Op = O_part + (size_t)z * NT * DMODEL;
#pragma unroll
    for (int g = 0; g < 2; ++g)
#pragma unroll
        for (int j = 0; j < 4; ++j) {
            const int r = qbase + wave * 32 + g * 16 + quad * 4 + j;
            if (r < NT) {
#pragma unroll
                for (int t = 0; t < 4; ++t)
                    Op[(size_t)r * DMODEL + hoff + t * 16 + l16] =
                        __float2bfloat16(accO[g][t][j]);
                if (l16 == 0)
                    l_part[((size_t)z * NHEAD + h) * NTP + r] = accL[g][j];
            }
        }
}

// ---------------------------------------------------------------------------
// Reduce kv-splits + per-head normalize + LayerNorm. grid = (NT), 192 thr.
// Each thread owns 4 consecutive dims (ushort4 bf16 loads; same head/quad).
// ---------------------------------------------------------------------------
__global__ __launch_bounds__(192) void reduce_ln_kernel(
    const bf16* __restrict__ O_part, const float* __restrict__ l_part,
    const float* __restrict__ g, const float* __restrict__ b,
    bf16* __restrict__ out, int nsplit) {
    const int n = blockIdx.x;
    const int tid = threadIdx.x;
    const int d0 = tid * 4;
    const int hh = d0 >> 6;

    float4 o = make_float4(0.f, 0.f, 0.f, 0.f);
    float lv = 0.f;
    for (int s = 0; s < nsplit; ++s) {
        ushort4 u = *(const ushort4*)(O_part + ((size_t)s * NT + n) * DMODEL + d0);
        o.x += bf16_to_f32(u.x); o.y += bf16_to_f32(u.y);
        o.z += bf16_to_f32(u.z); o.w += bf16_to_f32(u.w);
        lv += l_part[((size_t)s * NHEAD + hh) * NTP + n];
    }
    const float inv_l = 1.0f / lv;
    float vals[4] = {o.x * inv_l, o.y * inv_l, o.z * inv_l, o.w * inv_l};

    float s = vals[0] + vals[1] + vals[2] + vals[3];
    float s2 = vals[0] * vals[0] + vals[1] * vals[1] + vals[2] * vals[2] + vals[3] * vals[3];
#pragma unroll
    for (int off = 1; off < 64; off <<= 1) {
        s += __shfl_xor(s, off);
        s2 += __shfl_xor(s2, off);
    }
    __shared__ float ss[3], ss2[3];
    const int wave = tid >> 6, lane = tid & 63;
    if (lane == 0) { ss[wave] = s; ss2[wave] = s2; }
    __syncthreads();
    s = ss[0] + ss[1] + ss[2];
    s2 = ss2[0] + ss2[1] + ss2[2];
    const float mu = s * (1.0f / 768.0f);
    float var = s2 * (1.0f / 768.0f) - mu * mu;
    const float inv = rsqrtf(var + LN_EPS);

    unsigned short pk[4];
#pragma unroll
    for (int i = 0; i < 4; ++i) {
        const int d = d0 + i;
        const float v = (vals[i] - mu) * inv * g[d] + b[d];
        bf16 bb = __float2bfloat16(v);
        pk[i] = *(unsigned short*)&bb;
    }
    *(ushort4*)(out + (size_t)n * DMODEL + d0) = *(ushort4*)pk;
}

// ---------------------------------------------------------------------------
// Output projection v3 (R10 measured-best): 128-row blocks, region-select.
// grid = (34, 12). (256,4) reg cap. Reg-staged, 2-sync per K-step. fp32 out.
// (v4's gload+1-barrier variant measured +2.7us slower at 24 short K-steps.)
// ---------------------------------------------------------------------------
__global__ __launch_bounds__(256, 4) void out_kernel(
    const bf16* __restrict__ Lb, const bf16* __restrict__ wo,
    const float* __restrict__ bo_p, const float* __restrict__ bo_d,
    float* __restrict__ out) {
    __shared__ bf16 As[128][32];
    __shared__ bf16 Bs[64][32];

    const int tid = threadIdx.x;
    const int wave = tid >> 6, lane = tid & 63;
    const int quad = lane >> 4, l16 = lane & 15;
    const int bx = blockIdx.x;
    const int is_det = bx >= 33;
    const int row0 = is_det ? NP : bx * 128;
    const int Mlim = is_det ? NT : NP;
    const int col0 = blockIdx.y * 64;
    const size_t nw = (size_t)DMODEL * DMODEL;
    const bf16* B = wo + (is_det ? nw : 0);
    const float* bias = is_det ? bo_d : bo_p;

    const f32x4 z4 = {0.f, 0.f, 0.f, 0.f};
    f32x4 acc[2][4];
#pragma unroll
    for (int gg = 0; gg < 2; ++gg)
#pragma unroll
        for (int t = 0; t < 4; ++t) acc[gg][t] = z4;

    // staging: As 128x32 (2 uint4/thread, same row), Bs 64x32 (1 uint4/thread)
    const int arow = tid >> 1;              // 0..127
    const int acol = (tid & 1) * 16;        // 0 or 16
    int a_r = row0 + arow;
    if (a_r >= Mlim) a_r = Mlim - 1;
    const bf16* ap = Lb + (size_t)a_r * DMODEL + acol;
    const int brow = tid >> 2;              // 0..63
    const int bcol = (tid & 3) * 8;
    const bf16* bp = B + (size_t)(col0 + brow) * DMODEL + bcol;

    uint4 areg0 = *(const uint4*)(ap);
    uint4 areg1 = *(const uint4*)(ap + 8);
    uint4 breg  = *(const uint4*)(bp);

    for (int k0 = 0; k0 < DMODEL; k0 += 32) {
        __syncthreads();
        *(uint4*)(&As[arow][acol]) = areg0;
        *(uint4*)(&As[arow][acol + 8]) = areg1;
        *(uint4*)(&Bs[brow][bcol]) = breg;
        if (k0 + 32 < DMODEL) {
            areg0 = *(const uint4*)(ap + k0 + 32);
            areg1 = *(const uint4*)(ap + k0 + 40);
            breg  = *(const uint4*)(bp + k0 + 32);
        }
        __asm__ volatile("s_waitcnt lgkmcnt(0)" ::: "memory");
        __builtin_amdgcn_s_barrier();
        __asm__ volatile("" ::: "memory");
        frag8 af[2], bfq[4];
#pragma unroll
        for (int gg = 0; gg < 2; ++gg)
            af[gg] = *(const frag8*)(&As[wave * 32 + gg * 16 + l16][quad * 8]);
#pragma unroll
        for (int t = 0; t < 4; ++t)
            bfq[t] = *(const frag8*)(&Bs[t * 16 + l16][quad * 8]);
#pragma unroll
        for (int gg = 0; gg < 2; ++gg)
#pragma unroll
            for (int t = 0; t < 4; ++t)
                acc[gg][t] = __builtin_amdgcn_mfma_f32_16x16x32_bf16(af[gg], bfq[t], acc[gg][t], 0, 0, 0);
        __asm__ volatile("" ::: "memory");
    }

#pragma unroll
    for (int gg = 0; gg < 2; ++gg) {
        const int rbase = row0 + wave * 32 + gg * 16 + quad * 4;
#pragma unroll
        for (int t = 0; t < 4; ++t) {
            const int c = col0 + t * 16 + l16;
            const float bv = bias[c];
#pragma unroll
            for (int j = 0; j < 4; ++j) {
                const int r = rbase + j;
                if (r < Mlim) out[(size_t)r * DMODEL + c] = acc[gg][t][j] + bv;
            }
        }
    }
}

// ---------------------------------------------------------------------------
extern "C" void kernel_launch(void* const* d_in, const int* in_sizes, int n_in,
                              void* d_out, int out_size, void* d_ws, size_t ws_size,
                              hipStream_t stream) {
    const float* x    = (const float*)d_in[0];
    const float* wq_p = (const float*)d_in[1];
    const float* wk_p = (const float*)d_in[2];
    const float* wv_p = (const float*)d_in[3];
    const float* wq_d = (const float*)d_in[4];
    const float* wk_d = (const float*)d_in[5];
    const float* wv_d = (const float*)d_in[6];
    const float* bq_p = (const float*)d_in[7];
    const float* bv_p = (const float*)d_in[8];
    const float* bq_d = (const float*)d_in[9];
    const float* bv_d = (const float*)d_in[10];
    const float* ln_g = (const float*)d_in[11];
    const float* ln_b = (const float*)d_in[12];
    const float* wo_p = (const float*)d_in[13];
    const float* bo_p = (const float*)d_in[14];
    const float* wo_d = (const float*)d_in[15];
    const float* bo_d = (const float*)d_in[16];
    float* out = (float*)d_out;

    const size_t nx  = (size_t)NT * DMODEL;       // 3,303,168
    const size_t nsw = (size_t)NHEAD * NCHUNK * CHUNKSZ;  // 3,342,336
    const size_t nw  = (size_t)DMODEL * DMODEL;   // 589,824

    // fixed region
    char* ws = (char*)d_ws;
    bf16* xb   = (bf16*)ws; ws += nx * 2;         // reused as Lb after qkv
    bf16* wqkv = (bf16*)ws; ws += 6 * nw * 2;
    bf16* wob  = (bf16*)ws; ws += 2 * nw * 2;
    bf16* Qb   = (bf16*)ws; ws += nx * 2;
    bf16* Ksw  = (bf16*)ws; ws += nsw * 2;
    bf16* Vsw  = (bf16*)ws; ws += nsw * 2;
    const size_t fixed = (size_t)(ws - (char*)d_ws);

    // per-split region: O_part (bf16 NT x 768) + l_part (fp32 12 x NTP).
    // nsplit=4: 1632-block attn grid = 6.4 blocks/CU, fine tail granularity
    // (nsplit=2's 816 blocks = 3.2/CU cost +5.5us imbalance, R12 measured).
    const size_t per_split = nx * 2 + (size_t)NHEAD * NTP * 4;
    int nsplit = 1;
    if (ws_size >= fixed + 4 * per_split) nsplit = 4;
    else if (ws_size >= fixed + 2 * per_split) nsplit = 2;
    const int cpb = NCHUNK / nsplit;              // 68 divisible by 1/2/4

    bf16* O_part  = (bf16*)ws;
    float* l_part = (float*)(ws + (size_t)nsplit * nx * 2);
    bf16* Lb = xb;   // xb dead after qkv_kernel

    const int total = (int)(nx + 8 * nw);
    cast_all_kernel<<<dim3((total / 4 + 255) / 256), dim3(256), 0, stream>>>(
        x, wq_p, wk_p, wv_p, wq_d, wk_d, wv_d, wo_p, wo_d, xb, (int)nx, (int)nw, total);

    qkv_kernel<<<dim3(68, 12), dim3(256), 0, stream>>>(
        xb, wqkv, bq_p, bq_d, bv_p, bv_d, Qb, Ksw, Vsw);

    attn_kernel<<<dim3(34 * NHEAD * nsplit), dim3(256), 0, stream>>>(
        Qb, Ksw, Vsw, O_part, l_part, cpb);

    reduce_ln_kernel<<<dim3(NT), dim3(192), 0, stream>>>(
        O_part, l_part, ln_g, ln_b, Lb, nsplit);

    out_kernel<<<dim3(34, 12), dim3(256), 0, stream>>>(Lb, wob, bo_p, bo_d, out);
}